// Round 7
// baseline (9836.282 us; speedup 1.0000x reference)
//
#include <hip/hip_runtime.h>
#include <hip/hip_bf16.h>

// Problem constants
#define TT 512
#define BB 256
#define II 120
#define HH 128
#define GG 512   // 4*H
#define D1 512
#define NOUT 7
#define TB (TT*BB)  // 131072

typedef _Float16 f16x2 __attribute__((ext_vector_type(2)));
typedef _Float16 f16x8 __attribute__((ext_vector_type(8)));

// ---------- static device scratch ----------
__device__ unsigned short g_xg[(size_t)TB * GG];   // [T*B, 512] bf16 (layer-0 input proj)
__device__ float          g_pooled[BB * HH];

// ---------- helpers ----------
__device__ inline float bf2f(unsigned short u) {
    return __uint_as_float(((unsigned)u) << 16);
}
__device__ inline unsigned short f2bf(float f) {
    unsigned u = __float_as_uint(f);
    return (unsigned short)((u + 0x7fffu + ((u >> 16) & 1u)) >> 16);
}
__device__ inline float sigm(float x) {
    return 1.0f / (1.0f + __expf(-x));
}
__device__ inline float tanh_fast(float x) {
    x = fminf(fmaxf(x, -15.f), 15.f);
    float e = __expf(2.f * x);
    return (e - 1.f) / (e + 1.f);
}
__device__ inline float fdot2(f16x2 a, f16x2 b, float c) {
#if __has_builtin(__builtin_amdgcn_fdot2)
    return __builtin_amdgcn_fdot2(a, b, c, false);
#else
    return c + (float)a[0] * (float)b[0] + (float)a[1] * (float)b[1];
#endif
}
// quad broadcast: value of lane (q*4+L) to all 4 lanes of the quad — pure VALU DPP
template <int L>
__device__ inline float qb(float v) {
#if __has_builtin(__builtin_amdgcn_mov_dpp)
    return __int_as_float(
        __builtin_amdgcn_mov_dpp(__float_as_int(v), L * 0x55, 0xf, 0xf, true));
#else
    return __shfl(v, L, 4);
#endif
}

// ---------- GEMM0: xg[n,g] = sum_k x[n,k] * W_ih0[g,k] + b_ih0[g] + b_hh0[g] ----------
#define KC 32
__global__ __launch_bounds__(256) void gemm_xg_kernel(
    const float* __restrict__ A0,     // [TB, 120]
    const float* __restrict__ W,      // [512, 120]
    const float* __restrict__ bia,
    const float* __restrict__ bib)
{
    const int F  = II;
    const int m0 = blockIdx.x * 128;
    const int c0 = blockIdx.y * 128;
    const int t  = threadIdx.x;
    const int rg = t >> 4;
    const int cg = t & 15;

    __shared__ __align__(16) float As[KC][132];
    __shared__ __align__(16) float Ws[KC][132];

    float acc[8][8];
#pragma unroll
    for (int r = 0; r < 8; ++r)
#pragma unroll
        for (int c = 0; c < 8; ++c) acc[r][c] = 0.f;

    const int nchunk = (F + KC - 1) / KC;   // 4
    for (int ch = 0; ch < nchunk; ++ch) {
        const int k0 = ch * KC;
#pragma unroll
        for (int i = 0; i < 4; ++i) {
            int lin = t + i * 256;
            int kv  = lin & 7;
            int row = lin >> 3;
            int k = k0 + kv * 4;
            float4 v = make_float4(0.f, 0.f, 0.f, 0.f);
            if (k < F) v = *(const float4*)&A0[(size_t)(m0 + row) * II + k];
            As[kv * 4 + 0][row] = v.x;
            As[kv * 4 + 1][row] = v.y;
            As[kv * 4 + 2][row] = v.z;
            As[kv * 4 + 3][row] = v.w;
        }
#pragma unroll
        for (int i = 0; i < 4; ++i) {
            int lin = t + i * 256;
            int kv  = lin & 7;
            int col = lin >> 3;
            int k = k0 + kv * 4;
            float4 v = make_float4(0.f, 0.f, 0.f, 0.f);
            if (k < F) v = *(const float4*)&W[(size_t)(c0 + col) * F + k];
            Ws[kv * 4 + 0][col] = v.x;
            Ws[kv * 4 + 1][col] = v.y;
            Ws[kv * 4 + 2][col] = v.z;
            Ws[kv * 4 + 3][col] = v.w;
        }
        __syncthreads();
#pragma unroll 4
        for (int kk = 0; kk < KC; ++kk) {
            float4 a0 = *(const float4*)&As[kk][rg * 8];
            float4 a1 = *(const float4*)&As[kk][rg * 8 + 4];
            float4 w0 = *(const float4*)&Ws[kk][cg * 8];
            float4 w1 = *(const float4*)&Ws[kk][cg * 8 + 4];
            float av[8] = {a0.x, a0.y, a0.z, a0.w, a1.x, a1.y, a1.z, a1.w};
            float wv[8] = {w0.x, w0.y, w0.z, w0.w, w1.x, w1.y, w1.z, w1.w};
#pragma unroll
            for (int r = 0; r < 8; ++r)
#pragma unroll
                for (int c = 0; c < 8; ++c)
                    acc[r][c] += av[r] * wv[c];
        }
        __syncthreads();
    }

    float bcv[8];
#pragma unroll
    for (int c = 0; c < 8; ++c) {
        int col = c0 + cg * 8 + c;
        bcv[c] = bia[col] + bib[col];
    }
#pragma unroll
    for (int r = 0; r < 8; ++r) {
        int row = m0 + rg * 8 + r;
        ushort4 o0, o1;
        o0.x = f2bf(acc[r][0] + bcv[0]);
        o0.y = f2bf(acc[r][1] + bcv[1]);
        o0.z = f2bf(acc[r][2] + bcv[2]);
        o0.w = f2bf(acc[r][3] + bcv[3]);
        o1.x = f2bf(acc[r][4] + bcv[4]);
        o1.y = f2bf(acc[r][5] + bcv[5]);
        o1.z = f2bf(acc[r][6] + bcv[6]);
        o1.w = f2bf(acc[r][7] + bcv[7]);
        *(ushort4*)&g_xg[(size_t)row * GG + c0 + cg * 8]     = o0;
        *(ushort4*)&g_xg[(size_t)row * GG + c0 + cg * 8 + 4] = o1;
    }
}

// ---------- Fused 2-layer LSTM recurrence, L1 pipelined 1 step behind L0 ----------
// Thread t -> (unit u = t>>2, part p = t&3), gate row r = p*128+u.
//
// REGISTER-CAP LAW (measured r1/r3/r5/r6): default cap = 65536/threads
// (2 blocks/CU budget: 256t->256, 512t->128, 1024t->64), and
// __launch_bounds__'s 2nd arg acts as min-BLOCKS-per-CU (CUDA semantics):
// (512,2) -> cap 128 (measured r5). We need ~230 VGPRs (192 f16x2 weights +
// temps), so request 1 block/CU explicitly via raw attributes:
// waves_per_eu(2,2) with a 512-thread (8-wave) block = 1 block/CU -> cap 256.
__global__ __attribute__((amdgpu_flat_work_group_size(512, 512),
                          amdgpu_waves_per_eu(2, 2)))
void lstm_fused_kernel(
    const float* __restrict__ Whh0,   // [512,128]
    const float* __restrict__ Wih1,   // [512,128]
    const float* __restrict__ Whh1,   // [512,128]
    const float* __restrict__ bi1,
    const float* __restrict__ bh1,
    const int* __restrict__ lens)
{
    const int b = blockIdx.x;
    const int t = threadIdx.x;
    const int u = t >> 2;
    const int p = t & 3;
    const int r = p * 128 + u;

    __shared__ __align__(16) _Float16 h0buf[2][HH];
    __shared__ __align__(16) _Float16 h1buf[2][HH];

    f16x2 w0[64], wi[64], wh[64];
#pragma unroll
    for (int k4 = 0; k4 < 32; ++k4) {
        float4 v0 = *(const float4*)&Whh0[(size_t)r * HH + k4 * 4];
        w0[k4 * 2 + 0] = f16x2{(_Float16)v0.x, (_Float16)v0.y};
        w0[k4 * 2 + 1] = f16x2{(_Float16)v0.z, (_Float16)v0.w};
        float4 vi = *(const float4*)&Wih1[(size_t)r * HH + k4 * 4];
        wi[k4 * 2 + 0] = f16x2{(_Float16)vi.x, (_Float16)vi.y};
        wi[k4 * 2 + 1] = f16x2{(_Float16)vi.z, (_Float16)vi.w};
        float4 vh = *(const float4*)&Whh1[(size_t)r * HH + k4 * 4];
        wh[k4 * 2 + 0] = f16x2{(_Float16)vh.x, (_Float16)vh.y};
        wh[k4 * 2 + 1] = f16x2{(_Float16)vh.z, (_Float16)vh.w};
    }
    const float bias1 = bi1[r] + bh1[r];
    if (t < HH) {
        h0buf[0][t] = (_Float16)0.f; h0buf[1][t] = (_Float16)0.f;
        h1buf[0][t] = (_Float16)0.f; h1buf[1][t] = (_Float16)0.f;
    }
    float c0 = 0.f, c1 = 0.f, pool = 0.f;
    const int len = lens[b];
    __syncthreads();

    const unsigned short* xp = g_xg + (size_t)b * GG + r;
    const size_t xstride = (size_t)BB * GG;

    float xcur = bf2f(xp[0]);

    // ---- k = 0: layer-0 only (h0[-1]=0 in buf 1, write h0[0] to buf 0) ----
    {
        float aa0 = xcur, aa1 = 0.f, aa2 = 0.f, aa3 = 0.f;
#pragma unroll
        for (int k8 = 0; k8 < 16; ++k8) {
            f16x8 hv = *(const f16x8*)&h0buf[1][k8 * 8];
            aa0 = fdot2(w0[k8 * 4 + 0], f16x2{hv[0], hv[1]}, aa0);
            aa1 = fdot2(w0[k8 * 4 + 1], f16x2{hv[2], hv[3]}, aa1);
            aa2 = fdot2(w0[k8 * 4 + 2], f16x2{hv[4], hv[5]}, aa2);
            aa3 = fdot2(w0[k8 * 4 + 3], f16x2{hv[6], hv[7]}, aa3);
        }
        float acc = (aa0 + aa1) + (aa2 + aa3);
        float act = (p == 2) ? tanh_fast(acc) : sigm(acc);
        float i_ = qb<0>(act), f_ = qb<1>(act), g_ = qb<2>(act), o_ = qb<3>(act);
        c0 = f_ * c0 + i_ * g_;
        float hvv = o_ * tanh_fast(c0);
        if (p == 0) h0buf[0][u] = (_Float16)hvv;
    }
    __syncthreads();
    xcur = bf2f(xp[xstride]);

    // ---- main loop: k = 1..TT-1 : L0 step k + L1 step k-1 ----
    for (int k = 1; k < TT; ++k) {
        float xnext = (k + 1 < TT) ? bf2f(xp[(size_t)(k + 1) * xstride]) : 0.f;
        const int wr = k & 1, rd = wr ^ 1;

        float aa0 = xcur, aa1 = 0.f, aa2 = 0.f, aa3 = 0.f;       // L0 step k
        float bb0 = bias1, bb1 = 0.f, bb2 = 0.f, bb3 = 0.f;      // L1 step k-1
        // merged: one h0[k-1] LDS read feeds both w0 and wi dots
#pragma unroll
        for (int k8 = 0; k8 < 16; ++k8) {
            f16x8 hv = *(const f16x8*)&h0buf[rd][k8 * 8];
            f16x2 h01 = {hv[0], hv[1]}, h23 = {hv[2], hv[3]};
            f16x2 h45 = {hv[4], hv[5]}, h67 = {hv[6], hv[7]};
            aa0 = fdot2(w0[k8 * 4 + 0], h01, aa0);
            aa1 = fdot2(w0[k8 * 4 + 1], h23, aa1);
            aa2 = fdot2(w0[k8 * 4 + 2], h45, aa2);
            aa3 = fdot2(w0[k8 * 4 + 3], h67, aa3);
            bb0 = fdot2(wi[k8 * 4 + 0], h01, bb0);
            bb1 = fdot2(wi[k8 * 4 + 1], h23, bb1);
            bb2 = fdot2(wi[k8 * 4 + 2], h45, bb2);
            bb3 = fdot2(wi[k8 * 4 + 3], h67, bb3);
        }
        // h1[k-2] recurrent dot
#pragma unroll
        for (int k8 = 0; k8 < 16; ++k8) {
            f16x8 hv = *(const f16x8*)&h1buf[wr][k8 * 8];
            bb0 = fdot2(wh[k8 * 4 + 0], f16x2{hv[0], hv[1]}, bb0);
            bb1 = fdot2(wh[k8 * 4 + 1], f16x2{hv[2], hv[3]}, bb1);
            bb2 = fdot2(wh[k8 * 4 + 2], f16x2{hv[4], hv[5]}, bb2);
            bb3 = fdot2(wh[k8 * 4 + 3], f16x2{hv[6], hv[7]}, bb3);
        }

        // L0 cell update
        float accA = (aa0 + aa1) + (aa2 + aa3);
        float actA = (p == 2) ? tanh_fast(accA) : sigm(accA);
        float iA = qb<0>(actA), fA = qb<1>(actA), gA = qb<2>(actA), oA = qb<3>(actA);
        c0 = fA * c0 + iA * gA;
        float h0n = oA * tanh_fast(c0);

        // L1 cell update (step k-1)
        float accB = (bb0 + bb1) + (bb2 + bb3);
        float actB = (p == 2) ? tanh_fast(accB) : sigm(accB);
        float iB = qb<0>(actB), fB = qb<1>(actB), gB = qb<2>(actB), oB = qb<3>(actB);
        c1 = fB * c1 + iB * gB;
        float h1n = oB * tanh_fast(c1);
        if (k - 1 < len) {
            float ah = fabsf(h1n);
            pool += ah * sqrtf(ah);   // |h|^1.5
        }

        if (p == 0) {
            h0buf[wr][u] = (_Float16)h0n;
            h1buf[rd][u] = (_Float16)h1n;
        }
        __syncthreads();
        xcur = xnext;
    }

    // ---- epilogue: L1 step TT-1 (h0[511] in buf 1, h1[510] in buf 0) ----
    {
        float bb0 = bias1, bb1 = 0.f, bb2 = 0.f, bb3 = 0.f;
#pragma unroll
        for (int k8 = 0; k8 < 16; ++k8) {
            f16x8 h0v = *(const f16x8*)&h0buf[1][k8 * 8];
            f16x8 h1v = *(const f16x8*)&h1buf[0][k8 * 8];
            bb0 = fdot2(wi[k8 * 4 + 0], f16x2{h0v[0], h0v[1]}, bb0);
            bb1 = fdot2(wi[k8 * 4 + 1], f16x2{h0v[2], h0v[3]}, bb1);
            bb2 = fdot2(wi[k8 * 4 + 2], f16x2{h0v[4], h0v[5]}, bb2);
            bb3 = fdot2(wi[k8 * 4 + 3], f16x2{h0v[6], h0v[7]}, bb3);
            bb0 = fdot2(wh[k8 * 4 + 0], f16x2{h1v[0], h1v[1]}, bb0);
            bb1 = fdot2(wh[k8 * 4 + 1], f16x2{h1v[2], h1v[3]}, bb1);
            bb2 = fdot2(wh[k8 * 4 + 2], f16x2{h1v[4], h1v[5]}, bb2);
            bb3 = fdot2(wh[k8 * 4 + 3], f16x2{h1v[6], h1v[7]}, bb3);
        }
        float acc = (bb0 + bb1) + (bb2 + bb3);
        float act = (p == 2) ? tanh_fast(acc) : sigm(acc);
        float i_ = qb<0>(act), f_ = qb<1>(act), g_ = qb<2>(act), o_ = qb<3>(act);
        c1 = f_ * c1 + i_ * g_;
        float h1n = o_ * tanh_fast(c1);
        if (TT - 1 < len) {
            float ah = fabsf(h1n);
            pool += ah * sqrtf(ah);
        }
    }

    if (p == 0) {
        float s = powf(pool, 2.f / 3.f) * powf((float)len, -2.f / 3.f);
        g_pooled[b * HH + u] = s;
    }
}

// ---------- MLP + softmax ----------
__global__ __launch_bounds__(512) void mlp_kernel(
    const float* __restrict__ W1, const float* __restrict__ b1,
    const float* __restrict__ W2, const float* __restrict__ b2,
    float* __restrict__ out)
{
    const int b = blockIdx.x;
    const int t = threadIdx.x;
    __shared__ __align__(16) float pl[HH];
    __shared__ float x1[D1];
    __shared__ float lg[NOUT];

    if (t < HH) pl[t] = g_pooled[b * HH + t];
    __syncthreads();

    float acc = b1[t];
#pragma unroll
    for (int k4 = 0; k4 < 32; ++k4) {
        float4 wv = *(const float4*)&W1[(size_t)t * HH + k4 * 4];
        float4 pv = *(const float4*)&pl[k4 * 4];
        acc += wv.x * pv.x + wv.y * pv.y + wv.z * pv.z + wv.w * pv.w;
    }
    x1[t] = fmaxf(acc, 0.f);
    __syncthreads();

    if (t < NOUT) {
        float a = b2[t];
        for (int d = 0; d < D1; ++d) a += x1[d] * W2[(size_t)t * D1 + d];
        lg[t] = a;
    }
    __syncthreads();
    if (t < NOUT) {
        float m = lg[0];
#pragma unroll
        for (int j = 1; j < NOUT; ++j) m = fmaxf(m, lg[j]);
        float s = 0.f;
#pragma unroll
        for (int j = 0; j < NOUT; ++j) s += __expf(lg[j] - m);
        out[b * NOUT + t] = __expf(lg[t] - m) / s;
    }
}

// ---------- launch ----------
extern "C" void kernel_launch(void* const* d_in, const int* in_sizes, int n_in,
                              void* d_out, int out_size, void* d_ws, size_t ws_size,
                              hipStream_t stream)
{
    const float* x      = (const float*)d_in[0];
    const int*   lens   = (const int*)d_in[1];
    const float* W_ih0  = (const float*)d_in[2];
    const float* W_hh0  = (const float*)d_in[3];
    const float* b_ih0  = (const float*)d_in[4];
    const float* b_hh0  = (const float*)d_in[5];
    const float* W_ih1  = (const float*)d_in[6];
    const float* W_hh1  = (const float*)d_in[7];
    const float* b_ih1  = (const float*)d_in[8];
    const float* b_hh1  = (const float*)d_in[9];
    const float* W1     = (const float*)d_in[10];
    const float* b1     = (const float*)d_in[11];
    const float* W2     = (const float*)d_in[12];
    const float* b2     = (const float*)d_in[13];
    float* out = (float*)d_out;

    dim3 gg(TB / 128, GG / 128);   // (1024, 4)
    gemm_xg_kernel<<<gg, 256, 0, stream>>>(x, W_ih0, b_ih0, b_hh0);
    lstm_fused_kernel<<<BB, 512, 0, stream>>>(W_hh0, W_ih1, W_hh1, b_ih1, b_hh1, lens);
    mlp_kernel<<<BB, 512, 0, stream>>>(W1, b1, W2, b2, out);
}

// Round 8
// 1085.775 us; speedup vs baseline: 9.0592x; 9.0592x over previous
//
#include <hip/hip_runtime.h>
#include <hip/hip_bf16.h>

// Problem constants
#define TT 512
#define BB 256
#define II 120
#define HH 128
#define GG 512   // 4*H
#define D1 512
#define NOUT 7
#define TB (TT*BB)  // 131072

typedef _Float16 f16x2 __attribute__((ext_vector_type(2)));
typedef _Float16 f16x8 __attribute__((ext_vector_type(8)));

// ---------- static device scratch ----------
__device__ unsigned short g_xg[(size_t)TB * GG];   // [T*B, 512] bf16
__device__ unsigned short g_h0[(size_t)TB * HH];   // [T*B, 128] bf16
__device__ float          g_pooled[BB * HH];

// ---------- helpers ----------
__device__ inline float bf2f(unsigned short u) {
    return __uint_as_float(((unsigned)u) << 16);
}
__device__ inline unsigned short f2bf(float f) {
    unsigned u = __float_as_uint(f);
    return (unsigned short)((u + 0x7fffu + ((u >> 16) & 1u)) >> 16);
}
__device__ inline float sigm(float x) {
    return 1.0f / (1.0f + __expf(-x));
}
__device__ inline float tanh_fast(float x) {
    x = fminf(fmaxf(x, -15.f), 15.f);
    float e = __expf(2.f * x);
    return (e - 1.f) / (e + 1.f);
}
__device__ inline float fdot2(f16x2 a, f16x2 b, float c) {
#if __has_builtin(__builtin_amdgcn_fdot2)
    return __builtin_amdgcn_fdot2(a, b, c, false);
#else
    return c + (float)a[0] * (float)b[0] + (float)a[1] * (float)b[1];
#endif
}
// quad lane-xor moves via DPP quad_perm (pure VALU, no LDS pipe)
__device__ inline float dpp_xor1(float v) {
#if __has_builtin(__builtin_amdgcn_mov_dpp)
    return __int_as_float(
        __builtin_amdgcn_mov_dpp(__float_as_int(v), 0xB1, 0xf, 0xf, true)); // [1,0,3,2]
#else
    return __shfl_xor(v, 1, 4);
#endif
}
__device__ inline float dpp_xor2(float v) {
#if __has_builtin(__builtin_amdgcn_mov_dpp)
    return __int_as_float(
        __builtin_amdgcn_mov_dpp(__float_as_int(v), 0x4E, 0xf, 0xf, true)); // [2,3,0,1]
#else
    return __shfl_xor(v, 2, 4);
#endif
}
// quad broadcast lane L
template <int L>
__device__ inline float qb(float v) {
#if __has_builtin(__builtin_amdgcn_mov_dpp)
    return __int_as_float(
        __builtin_amdgcn_mov_dpp(__float_as_int(v), L * 0x55, 0xf, 0xf, true));
#else
    return __shfl(v, L, 4);
#endif
}

// ---------- GEMM: xg[n,g] = sum_k A[n,k] * W[g,k] + bia[g] + bib[g] ----------
// 128x128 tile per 256-thread block; 8x8 micro-tile; K chunked by 32.
// LAYER 0: A = input_seq (f32, F=120); LAYER 1: A = g_h0 (bf16, F=128)
#define KC 32
template <int LAYER>
__global__ __launch_bounds__(256) void gemm_xg_kernel(
    const float* __restrict__ A0,
    const float* __restrict__ W,      // [512, F]
    const float* __restrict__ bia,
    const float* __restrict__ bib)
{
    const int F  = (LAYER == 0) ? II : HH;
    const int m0 = blockIdx.x * 128;
    const int c0 = blockIdx.y * 128;
    const int t  = threadIdx.x;
    const int rg = t >> 4;
    const int cg = t & 15;

    __shared__ __align__(16) float As[KC][132];
    __shared__ __align__(16) float Ws[KC][132];

    float acc[8][8];
#pragma unroll
    for (int r = 0; r < 8; ++r)
#pragma unroll
        for (int c = 0; c < 8; ++c) acc[r][c] = 0.f;

    const int nchunk = (F + KC - 1) / KC;   // 4
    for (int ch = 0; ch < nchunk; ++ch) {
        const int k0 = ch * KC;
#pragma unroll
        for (int i = 0; i < 4; ++i) {
            int lin = t + i * 256;
            int kv  = lin & 7;
            int row = lin >> 3;
            int k = k0 + kv * 4;
            float4 v = make_float4(0.f, 0.f, 0.f, 0.f);
            if (k < F) {
                if (LAYER == 0) {
                    v = *(const float4*)&A0[(size_t)(m0 + row) * II + k];
                } else {
                    ushort4 uu = *(const ushort4*)&g_h0[(size_t)(m0 + row) * HH + k];
                    v = make_float4(bf2f(uu.x), bf2f(uu.y), bf2f(uu.z), bf2f(uu.w));
                }
            }
            As[kv * 4 + 0][row] = v.x;
            As[kv * 4 + 1][row] = v.y;
            As[kv * 4 + 2][row] = v.z;
            As[kv * 4 + 3][row] = v.w;
        }
#pragma unroll
        for (int i = 0; i < 4; ++i) {
            int lin = t + i * 256;
            int kv  = lin & 7;
            int col = lin >> 3;
            int k = k0 + kv * 4;
            float4 v = make_float4(0.f, 0.f, 0.f, 0.f);
            if (k < F) v = *(const float4*)&W[(size_t)(c0 + col) * F + k];
            Ws[kv * 4 + 0][col] = v.x;
            Ws[kv * 4 + 1][col] = v.y;
            Ws[kv * 4 + 2][col] = v.z;
            Ws[kv * 4 + 3][col] = v.w;
        }
        __syncthreads();
#pragma unroll 4
        for (int kk = 0; kk < KC; ++kk) {
            float4 a0 = *(const float4*)&As[kk][rg * 8];
            float4 a1 = *(const float4*)&As[kk][rg * 8 + 4];
            float4 w0 = *(const float4*)&Ws[kk][cg * 8];
            float4 w1 = *(const float4*)&Ws[kk][cg * 8 + 4];
            float av[8] = {a0.x, a0.y, a0.z, a0.w, a1.x, a1.y, a1.z, a1.w};
            float wv[8] = {w0.x, w0.y, w0.z, w0.w, w1.x, w1.y, w1.z, w1.w};
#pragma unroll
            for (int r = 0; r < 8; ++r)
#pragma unroll
                for (int c = 0; c < 8; ++c)
                    acc[r][c] += av[r] * wv[c];
        }
        __syncthreads();
    }

    float bcv[8];
#pragma unroll
    for (int c = 0; c < 8; ++c) {
        int col = c0 + cg * 8 + c;
        bcv[c] = bia[col] + bib[col];
    }
#pragma unroll
    for (int r = 0; r < 8; ++r) {
        int row = m0 + rg * 8 + r;
        ushort4 o0, o1;
        o0.x = f2bf(acc[r][0] + bcv[0]);
        o0.y = f2bf(acc[r][1] + bcv[1]);
        o0.z = f2bf(acc[r][2] + bcv[2]);
        o0.w = f2bf(acc[r][3] + bcv[3]);
        o1.x = f2bf(acc[r][4] + bcv[4]);
        o1.y = f2bf(acc[r][5] + bcv[5]);
        o1.z = f2bf(acc[r][6] + bcv[6]);
        o1.w = f2bf(acc[r][7] + bcv[7]);
        *(ushort4*)&g_xg[(size_t)row * GG + c0 + cg * 8]     = o0;
        *(ushort4*)&g_xg[(size_t)row * GG + c0 + cg * 8 + 4] = o1;
    }
}

// ---------- LSTM recurrence, quad-k-split ----------
// Thread t -> (unit u = t>>2, quad lane p = t&3).
// Weights (64 VGPR): slot j holds gate row (p^j)*128+u, k in [32p, 32p+32)
// (XOR-rotated so the quad transpose-combine needs no select).
// Per step: 4x ds_read_b128 (vs 16 in r3 -> 4x less DS-pipe pressure),
// 64 fdot2 in 4 indep 16-deep chains, then 3 DPP-xor adds give lane p the
// full preactivation of gate p. Gate exchange = DPP quad broadcast.
// One barrier/step; h double-buffered f16 in LDS.
template <int LAYER>
__global__ __launch_bounds__(512) void lstm_kernel(
    const float* __restrict__ Whh,   // [512,128]
    const int* __restrict__ lens)
{
    const int b = blockIdx.x;
    const int t = threadIdx.x;
    const int u = t >> 2;
    const int p = t & 3;

    __shared__ __align__(16) _Float16 h_lds[2][HH];

    f16x2 w[4][16];
#pragma unroll
    for (int j = 0; j < 4; ++j) {
        const int row = ((p ^ j) << 7) + u;          // gate (p^j), unit u
#pragma unroll
        for (int k4 = 0; k4 < 8; ++k4) {
            float4 v = *(const float4*)&Whh[(size_t)row * HH + (p << 5) + k4 * 4];
            w[j][k4 * 2 + 0] = f16x2{(_Float16)v.x, (_Float16)v.y};
            w[j][k4 * 2 + 1] = f16x2{(_Float16)v.z, (_Float16)v.w};
        }
    }
    if (t < HH) {
        h_lds[0][t] = (_Float16)0.f;
        h_lds[1][t] = (_Float16)0.f;
    }
    float c = 0.f, pool = 0.f;
    const int len = lens[b];
    __syncthreads();

    const unsigned short* xp = g_xg + (size_t)b * GG + (p * 128 + u);
    const size_t xstride = (size_t)BB * GG;
    float xcur = bf2f(xp[0]);

    for (int step = 0; step < TT; ++step) {
        float xnext = (step + 1 < TT) ? bf2f(xp[(size_t)(step + 1) * xstride]) : 0.f;
        const int rd = step & 1, wr = rd ^ 1;

        float pa0 = 0.f, pa1 = 0.f, pa2 = 0.f, pa3 = 0.f;
#pragma unroll
        for (int seg = 0; seg < 4; ++seg) {
            f16x8 hv = *(const f16x8*)&h_lds[rd][(p << 5) + seg * 8];
            f16x2 h01 = {hv[0], hv[1]}, h23 = {hv[2], hv[3]};
            f16x2 h45 = {hv[4], hv[5]}, h67 = {hv[6], hv[7]};
            pa0 = fdot2(w[0][seg * 4 + 0], h01, pa0);
            pa0 = fdot2(w[0][seg * 4 + 1], h23, pa0);
            pa0 = fdot2(w[0][seg * 4 + 2], h45, pa0);
            pa0 = fdot2(w[0][seg * 4 + 3], h67, pa0);
            pa1 = fdot2(w[1][seg * 4 + 0], h01, pa1);
            pa1 = fdot2(w[1][seg * 4 + 1], h23, pa1);
            pa1 = fdot2(w[1][seg * 4 + 2], h45, pa1);
            pa1 = fdot2(w[1][seg * 4 + 3], h67, pa1);
            pa2 = fdot2(w[2][seg * 4 + 0], h01, pa2);
            pa2 = fdot2(w[2][seg * 4 + 1], h23, pa2);
            pa2 = fdot2(w[2][seg * 4 + 2], h45, pa2);
            pa2 = fdot2(w[2][seg * 4 + 3], h67, pa2);
            pa3 = fdot2(w[3][seg * 4 + 0], h01, pa3);
            pa3 = fdot2(w[3][seg * 4 + 1], h23, pa3);
            pa3 = fdot2(w[3][seg * 4 + 2], h45, pa3);
            pa3 = fdot2(w[3][seg * 4 + 3], h67, pa3);
        }
        // quad transpose-combine (XOR-rotated layout):
        // after these 3 adds, lane p's pa0 = full dot for gate row p*128+u
        pa0 += dpp_xor1(pa1);
        pa2 += dpp_xor1(pa3);
        pa0 += dpp_xor2(pa2);

        float acc = pa0 + xcur;
        float act = (p == 2) ? tanh_fast(acc) : sigm(acc);
        float i_ = qb<0>(act), f_ = qb<1>(act), g_ = qb<2>(act), o_ = qb<3>(act);
        c = f_ * c + i_ * g_;
        float hvv = o_ * tanh_fast(c);

        if (LAYER == 0) {
            if (p == 0) g_h0[((size_t)step * BB + b) * HH + u] = f2bf(hvv);
        } else {
            if (step < len) {
                float ah = fabsf(hvv);
                pool += ah * sqrtf(ah);   // |h|^1.5
            }
        }
        if (p == 0) h_lds[wr][u] = (_Float16)hvv;
        __syncthreads();
        xcur = xnext;
    }

    if (LAYER == 1 && p == 0) {
        float s = powf(pool, 2.f / 3.f) * powf((float)len, -2.f / 3.f);
        g_pooled[b * HH + u] = s;
    }
}

// ---------- MLP + softmax ----------
__global__ __launch_bounds__(512) void mlp_kernel(
    const float* __restrict__ W1, const float* __restrict__ b1,
    const float* __restrict__ W2, const float* __restrict__ b2,
    float* __restrict__ out)
{
    const int b = blockIdx.x;
    const int t = threadIdx.x;
    __shared__ __align__(16) float pl[HH];
    __shared__ float x1[D1];
    __shared__ float lg[NOUT];

    if (t < HH) pl[t] = g_pooled[b * HH + t];
    __syncthreads();

    float acc = b1[t];
#pragma unroll
    for (int k4 = 0; k4 < 32; ++k4) {
        float4 wv = *(const float4*)&W1[(size_t)t * HH + k4 * 4];
        float4 pv = *(const float4*)&pl[k4 * 4];
        acc += wv.x * pv.x + wv.y * pv.y + wv.z * pv.z + wv.w * pv.w;
    }
    x1[t] = fmaxf(acc, 0.f);
    __syncthreads();

    if (t < NOUT) {
        float a = b2[t];
        for (int d = 0; d < D1; ++d) a += x1[d] * W2[(size_t)t * D1 + d];
        lg[t] = a;
    }
    __syncthreads();
    if (t < NOUT) {
        float m = lg[0];
#pragma unroll
        for (int j = 1; j < NOUT; ++j) m = fmaxf(m, lg[j]);
        float s = 0.f;
#pragma unroll
        for (int j = 0; j < NOUT; ++j) s += __expf(lg[j] - m);
        out[b * NOUT + t] = __expf(lg[t] - m) / s;
    }
}

// ---------- launch ----------
extern "C" void kernel_launch(void* const* d_in, const int* in_sizes, int n_in,
                              void* d_out, int out_size, void* d_ws, size_t ws_size,
                              hipStream_t stream)
{
    const float* x      = (const float*)d_in[0];
    const int*   lens   = (const int*)d_in[1];
    const float* W_ih0  = (const float*)d_in[2];
    const float* W_hh0  = (const float*)d_in[3];
    const float* b_ih0  = (const float*)d_in[4];
    const float* b_hh0  = (const float*)d_in[5];
    const float* W_ih1  = (const float*)d_in[6];
    const float* W_hh1  = (const float*)d_in[7];
    const float* b_ih1  = (const float*)d_in[8];
    const float* b_hh1  = (const float*)d_in[9];
    const float* W1     = (const float*)d_in[10];
    const float* b1     = (const float*)d_in[11];
    const float* W2     = (const float*)d_in[12];
    const float* b2     = (const float*)d_in[13];
    float* out = (float*)d_out;

    dim3 gg(TB / 128, GG / 128);   // (1024, 4)
    gemm_xg_kernel<0><<<gg, 256, 0, stream>>>(x, W_ih0, b_ih0, b_hh0);
    lstm_kernel<0><<<BB, 512, 0, stream>>>(W_hh0, lens);
    gemm_xg_kernel<1><<<gg, 256, 0, stream>>>(x, W_ih1, b_ih1, b_hh1);
    lstm_kernel<1><<<BB, 512, 0, stream>>>(W_hh1, lens);
    mlp_kernel<<<BB, 512, 0, stream>>>(W1, b1, W2, b2, out);
}

// Round 9
// 849.110 us; speedup vs baseline: 11.5842x; 1.2787x over previous
//
#include <hip/hip_runtime.h>
#include <hip/hip_bf16.h>

// Problem constants
#define TT 512
#define BB 256
#define II 120
#define HH 128
#define GG 512   // 4*H
#define D1 512
#define NOUT 7
#define TB (TT*BB)  // 131072
#define CH 64       // lstm x-stage chunk (steps)

typedef _Float16 f16x2 __attribute__((ext_vector_type(2)));
typedef _Float16 f16x4 __attribute__((ext_vector_type(4)));
typedef _Float16 f16x8 __attribute__((ext_vector_type(8)));
typedef float    f32x4 __attribute__((ext_vector_type(4)));
typedef unsigned short ushort8v __attribute__((ext_vector_type(8)));

// ---------- static device scratch ----------
__device__ unsigned short g_xg[(size_t)TB * GG];   // [T*B, 512] bf16
__device__ _Float16       g_h0[(size_t)TB * HH];   // [T*B, 128] f16
__device__ float          g_pooled[BB * HH];

// ---------- helpers ----------
__device__ inline float bf2f(unsigned short u) {
    return __uint_as_float(((unsigned)u) << 16);
}
__device__ inline unsigned short f2bf(float f) {
    unsigned u = __float_as_uint(f);
    return (unsigned short)((u + 0x7fffu + ((u >> 16) & 1u)) >> 16);
}
__device__ inline float sigm(float x) {
    return 1.0f / (1.0f + __expf(-x));
}
__device__ inline float tanh_fast(float x) {
    x = fminf(fmaxf(x, -15.f), 15.f);
    float e = __expf(2.f * x);
    return (e - 1.f) / (e + 1.f);
}
__device__ inline float fdot2(f16x2 a, f16x2 b, float c) {
#if __has_builtin(__builtin_amdgcn_fdot2)
    return __builtin_amdgcn_fdot2(a, b, c, false);
#else
    return c + (float)a[0] * (float)b[0] + (float)a[1] * (float)b[1];
#endif
}
__device__ inline float dpp_xor1(float v) {
#if __has_builtin(__builtin_amdgcn_mov_dpp)
    return __int_as_float(
        __builtin_amdgcn_mov_dpp(__float_as_int(v), 0xB1, 0xf, 0xf, true)); // [1,0,3,2]
#else
    return __shfl_xor(v, 1, 4);
#endif
}
__device__ inline float dpp_xor2(float v) {
#if __has_builtin(__builtin_amdgcn_mov_dpp)
    return __int_as_float(
        __builtin_amdgcn_mov_dpp(__float_as_int(v), 0x4E, 0xf, 0xf, true)); // [2,3,0,1]
#else
    return __shfl_xor(v, 2, 4);
#endif
}
template <int L>
__device__ inline float qb(float v) {
#if __has_builtin(__builtin_amdgcn_mov_dpp)
    return __int_as_float(
        __builtin_amdgcn_mov_dpp(__float_as_int(v), L * 0x55, 0xf, 0xf, true));
#else
    return __shfl(v, L, 4);
#endif
}

// ---------- MFMA GEMM: xg[n,g] = sum_k A[n,k]*W[g,k] + bia[g]+bib[g] ----------
// f16 MFMA 16x16x32. Block: 128(M)x128(N), 512 threads = 8 waves (2x4 of 64x32).
// A: LAYER0 = x (f32->f16 on stage), LAYER1 = g_h0 (f16). B = W rows (f32->f16).
// LDS padded [128][40] (stride 80B): frag-read conflicts <= 2-way (free).
// Fragments (m89/m91-verified family): A row=lane&15, k=(lane>>4)*8+j;
// B col=lane&15, same k; D col=lane&15, row=(lane>>4)*4+reg.
template <int LAYER>
__global__ __launch_bounds__(512) void gemm_mfma_kernel(
    const float* __restrict__ A0,     // [TB, II] (LAYER 0 only)
    const float* __restrict__ W,      // [512, F] f32
    const float* __restrict__ bia,
    const float* __restrict__ bib)
{
    const int F  = (LAYER == 0) ? II : HH;
    const int m0 = blockIdx.x * 128;
    const int n0 = blockIdx.y * 128;
    const int t    = threadIdx.x;
    const int lane = t & 63;
    const int wv   = t >> 6;         // 0..7
    const int wm   = wv >> 2;        // 0..1 -> rows wm*64
    const int wn   = wv & 3;         // 0..3 -> cols wn*32
    const int l15  = lane & 15;
    const int lhi  = lane >> 4;      // 0..3

    __shared__ _Float16 As[128][40];
    __shared__ _Float16 Bs[128][40];

    f32x4 acc[4][2];
#pragma unroll
    for (int mi = 0; mi < 4; ++mi)
#pragma unroll
        for (int ni = 0; ni < 2; ++ni)
            acc[mi][ni] = f32x4{0.f, 0.f, 0.f, 0.f};

    const int srow = t >> 2;   // staging row 0..127
    const int q    = t & 3;    // k-slot: covers k0+q*8 .. +7

#pragma unroll 1
    for (int kc = 0; kc < 4; ++kc) {
        const int k0 = kc * 32;
        // ---- stage A tile (128 x 32 f16) ----
        if (LAYER == 0) {
#pragma unroll
            for (int h = 0; h < 2; ++h) {
                int k = k0 + q * 8 + h * 4;
                float4 v = make_float4(0.f, 0.f, 0.f, 0.f);
                if (k + 4 <= F) v = *(const float4*)&A0[(size_t)(m0 + srow) * II + k];
                f16x4 hv = {(_Float16)v.x, (_Float16)v.y, (_Float16)v.z, (_Float16)v.w};
                *(f16x4*)&As[srow][q * 8 + h * 4] = hv;
            }
        } else {
            int k = k0 + q * 8;   // F=128: always valid
            f16x8 v = *(const f16x8*)&g_h0[(size_t)(m0 + srow) * HH + k];
            *(f16x8*)&As[srow][q * 8] = v;
        }
        // ---- stage B tile: W rows n0..n0+127, k chunk ----
#pragma unroll
        for (int h = 0; h < 2; ++h) {
            int k = k0 + q * 8 + h * 4;
            float4 v = make_float4(0.f, 0.f, 0.f, 0.f);
            if (k + 4 <= F) v = *(const float4*)&W[(size_t)(n0 + srow) * F + k];
            f16x4 hv = {(_Float16)v.x, (_Float16)v.y, (_Float16)v.z, (_Float16)v.w};
            *(f16x4*)&Bs[srow][q * 8 + h * 4] = hv;
        }
        __syncthreads();

        f16x8 af[4], bf[2];
#pragma unroll
        for (int mi = 0; mi < 4; ++mi)
            af[mi] = *(const f16x8*)&As[wm * 64 + mi * 16 + l15][lhi * 8];
#pragma unroll
        for (int ni = 0; ni < 2; ++ni)
            bf[ni] = *(const f16x8*)&Bs[wn * 32 + ni * 16 + l15][lhi * 8];
#pragma unroll
        for (int mi = 0; mi < 4; ++mi)
#pragma unroll
            for (int ni = 0; ni < 2; ++ni)
                acc[mi][ni] = __builtin_amdgcn_mfma_f32_16x16x32_f16(
                    af[mi], bf[ni], acc[mi][ni], 0, 0, 0);
        __syncthreads();
    }

    // ---- epilogue: bias + bf16 store ----
#pragma unroll
    for (int ni = 0; ni < 2; ++ni) {
        const int col = n0 + wn * 32 + ni * 16 + l15;
        const float bc = bia[col] + bib[col];
#pragma unroll
        for (int mi = 0; mi < 4; ++mi) {
#pragma unroll
            for (int j = 0; j < 4; ++j) {
                const int grow = m0 + wm * 64 + mi * 16 + lhi * 4 + j;
                g_xg[(size_t)grow * GG + col] = f2bf(acc[mi][ni][j] + bc);
            }
        }
    }
}

// ---------- LSTM recurrence, quad-k-split + chunked LDS x-staging ----------
// r8 structure (quad-k-split weights, DPP combines, 1 barrier/step) plus:
// xg staged into LDS in 64-step double-buffered chunks via coalesced ushort8
// reg-staging. Global loads exist only at 8 chunk boundaries, so the per-step
// __syncthreads vmcnt(0) drain (which cost ~450-900 cyc/step in r8 -- every
// step had an in-flight global x prefetch) disappears; drain cost is now
// ~2.6us x 8 chunks. Per-step x read = one 2B LDS read.
template <int LAYER>
__global__ __launch_bounds__(512) void lstm_kernel(
    const float* __restrict__ Whh,   // [512,128]
    const int* __restrict__ lens)
{
    const int b = blockIdx.x;
    const int t = threadIdx.x;
    const int u = t >> 2;
    const int p = t & 3;
    const int wave = t >> 6;
    const int lane = t & 63;
    const int r = p * 128 + u;       // this thread's gate row

    __shared__ __align__(16) _Float16 h_lds[2][HH];
    __shared__ __align__(16) unsigned short xstage[2][CH][GG];  // 128 KB

    // quad-k-split weights: slot j = gate (p^j), k in [32p, 32p+32)
    f16x2 w[4][16];
#pragma unroll
    for (int j = 0; j < 4; ++j) {
        const int row = ((p ^ j) << 7) + u;
#pragma unroll
        for (int k4 = 0; k4 < 8; ++k4) {
            float4 v = *(const float4*)&Whh[(size_t)row * HH + (p << 5) + k4 * 4];
            w[j][k4 * 2 + 0] = f16x2{(_Float16)v.x, (_Float16)v.y};
            w[j][k4 * 2 + 1] = f16x2{(_Float16)v.z, (_Float16)v.w};
        }
    }
    if (t < HH) {
        h_lds[0][t] = (_Float16)0.f;
        h_lds[1][t] = (_Float16)0.f;
    }
    float c = 0.f, pool = 0.f;
    const int len = lens[b];

    const unsigned short* xbase = g_xg + (size_t)b * GG;
    const size_t stepstride = (size_t)BB * GG;

    // stage chunk 0 (each wave loads 8 step-rows, coalesced 16B/lane)
    {
        ushort8v tmp[8];
#pragma unroll
        for (int j = 0; j < 8; ++j) {
            int sr = wave * 8 + j;
            tmp[j] = *(const ushort8v*)(xbase + (size_t)sr * stepstride + lane * 8);
        }
#pragma unroll
        for (int j = 0; j < 8; ++j)
            *(ushort8v*)&xstage[0][wave * 8 + j][lane * 8] = tmp[j];
    }
    __syncthreads();

#pragma unroll 1
    for (int ch = 0; ch < TT / CH; ++ch) {
        const int cur = ch & 1;
        if (ch + 1 < TT / CH) {   // prefetch next chunk into other buffer
            ushort8v tmp[8];
#pragma unroll
            for (int j = 0; j < 8; ++j) {
                int sr = (ch + 1) * CH + wave * 8 + j;
                tmp[j] = *(const ushort8v*)(xbase + (size_t)sr * stepstride + lane * 8);
            }
#pragma unroll
            for (int j = 0; j < 8; ++j)
                *(ushort8v*)&xstage[cur ^ 1][wave * 8 + j][lane * 8] = tmp[j];
        }
#pragma unroll 1
        for (int ls = 0; ls < CH; ++ls) {
            const int step = ch * CH + ls;
            const int rdb = step & 1, wrb = rdb ^ 1;
            const float xcur = bf2f(xstage[cur][ls][r]);

            float pa0 = 0.f, pa1 = 0.f, pa2 = 0.f, pa3 = 0.f;
#pragma unroll
            for (int seg = 0; seg < 4; ++seg) {
                f16x8 hv = *(const f16x8*)&h_lds[rdb][(p << 5) + seg * 8];
                f16x2 h01 = {hv[0], hv[1]}, h23 = {hv[2], hv[3]};
                f16x2 h45 = {hv[4], hv[5]}, h67 = {hv[6], hv[7]};
                pa0 = fdot2(w[0][seg * 4 + 0], h01, pa0);
                pa0 = fdot2(w[0][seg * 4 + 1], h23, pa0);
                pa0 = fdot2(w[0][seg * 4 + 2], h45, pa0);
                pa0 = fdot2(w[0][seg * 4 + 3], h67, pa0);
                pa1 = fdot2(w[1][seg * 4 + 0], h01, pa1);
                pa1 = fdot2(w[1][seg * 4 + 1], h23, pa1);
                pa1 = fdot2(w[1][seg * 4 + 2], h45, pa1);
                pa1 = fdot2(w[1][seg * 4 + 3], h67, pa1);
                pa2 = fdot2(w[2][seg * 4 + 0], h01, pa2);
                pa2 = fdot2(w[2][seg * 4 + 1], h23, pa2);
                pa2 = fdot2(w[2][seg * 4 + 2], h45, pa2);
                pa2 = fdot2(w[2][seg * 4 + 3], h67, pa2);
                pa3 = fdot2(w[3][seg * 4 + 0], h01, pa3);
                pa3 = fdot2(w[3][seg * 4 + 1], h23, pa3);
                pa3 = fdot2(w[3][seg * 4 + 2], h45, pa3);
                pa3 = fdot2(w[3][seg * 4 + 3], h67, pa3);
            }
            // quad transpose-combine: lane p ends with gate p's full dot
            pa0 += dpp_xor1(pa1);
            pa2 += dpp_xor1(pa3);
            pa0 += dpp_xor2(pa2);

            const float acc = pa0 + xcur;
            const float act = (p == 2) ? tanh_fast(acc) : sigm(acc);
            const float i_ = qb<0>(act), f_ = qb<1>(act),
                        g_ = qb<2>(act), o_ = qb<3>(act);
            c = f_ * c + i_ * g_;
            const float hvv = o_ * tanh_fast(c);

            if (LAYER == 0) {
                if (p == 0) g_h0[((size_t)step * BB + b) * HH + u] = (_Float16)hvv;
            } else {
                if (step < len) {
                    float ah = fabsf(hvv);
                    pool += ah * sqrtf(ah);   // |h|^1.5
                }
            }
            if (p == 0) h_lds[wrb][u] = (_Float16)hvv;
            __syncthreads();
        }
    }

    if (LAYER == 1 && p == 0) {
        float s = powf(pool, 2.f / 3.f) * powf((float)len, -2.f / 3.f);
        g_pooled[b * HH + u] = s;
    }
}

// ---------- MLP + softmax ----------
__global__ __launch_bounds__(512) void mlp_kernel(
    const float* __restrict__ W1, const float* __restrict__ b1,
    const float* __restrict__ W2, const float* __restrict__ b2,
    float* __restrict__ out)
{
    const int b = blockIdx.x;
    const int t = threadIdx.x;
    __shared__ __align__(16) float pl[HH];
    __shared__ float x1[D1];
    __shared__ float lg[NOUT];

    if (t < HH) pl[t] = g_pooled[b * HH + t];
    __syncthreads();

    float acc = b1[t];
#pragma unroll
    for (int k4 = 0; k4 < 32; ++k4) {
        float4 wv = *(const float4*)&W1[(size_t)t * HH + k4 * 4];
        float4 pv = *(const float4*)&pl[k4 * 4];
        acc += wv.x * pv.x + wv.y * pv.y + wv.z * pv.z + wv.w * pv.w;
    }
    x1[t] = fmaxf(acc, 0.f);
    __syncthreads();

    if (t < NOUT) {
        float a = b2[t];
        for (int d = 0; d < D1; ++d) a += x1[d] * W2[(size_t)t * D1 + d];
        lg[t] = a;
    }
    __syncthreads();
    if (t < NOUT) {
        float m = lg[0];
#pragma unroll
        for (int j = 1; j < NOUT; ++j) m = fmaxf(m, lg[j]);
        float s = 0.f;
#pragma unroll
        for (int j = 0; j < NOUT; ++j) s += __expf(lg[j] - m);
        out[b * NOUT + t] = __expf(lg[t] - m) / s;
    }
}

// ---------- launch ----------
extern "C" void kernel_launch(void* const* d_in, const int* in_sizes, int n_in,
                              void* d_out, int out_size, void* d_ws, size_t ws_size,
                              hipStream_t stream)
{
    const float* x      = (const float*)d_in[0];
    const int*   lens   = (const int*)d_in[1];
    const float* W_ih0  = (const float*)d_in[2];
    const float* W_hh0  = (const float*)d_in[3];
    const float* b_ih0  = (const float*)d_in[4];
    const float* b_hh0  = (const float*)d_in[5];
    const float* W_ih1  = (const float*)d_in[6];
    const float* W_hh1  = (const float*)d_in[7];
    const float* b_ih1  = (const float*)d_in[8];
    const float* b_hh1  = (const float*)d_in[9];
    const float* W1     = (const float*)d_in[10];
    const float* b1     = (const float*)d_in[11];
    const float* W2     = (const float*)d_in[12];
    const float* b2     = (const float*)d_in[13];
    float* out = (float*)d_out;

    dim3 gg(TB / 128, GG / 128);   // (1024, 4)
    gemm_mfma_kernel<0><<<gg, 512, 0, stream>>>(x, W_ih0, b_ih0, b_hh0);
    lstm_kernel<0><<<BB, 512, 0, stream>>>(W_hh0, lens);
    gemm_mfma_kernel<1><<<gg, 512, 0, stream>>>(x, W_ih1, b_ih1, b_hh1);
    lstm_kernel<1><<<BB, 512, 0, stream>>>(W_hh1, lens);
    mlp_kernel<<<BB, 512, 0, stream>>>(W1, b1, W2, b2, out);
}